// Round 1
// 816.764 us; speedup vs baseline: 1.0412x; 1.0412x over previous
//
#include <hip/hip_runtime.h>

// Problem constants (from reference)
#define ZDIM 64
#define CDIM 256
#define PDIM 4
#define BNODES 50000
#define LD 3
#define ROW (CDIM * LD)          // 768 f32 per (p,b) row
#define ALPHA 0.5f               // 1/sqrt(P) = 1/2

// 12-byte vector so clang emits a single global_load/store_dwordx3.
struct __align__(4) f3 { float x, y, z; };

// One wave (64 lanes) per node b.  All tensors float32.
//  - lane z reads node_attrs[b,z]; ballot finds the one-hot index (Z == 64 == wave)
//  - lane l owns channels c = j*64 + l, j = 0..3  -> EVERY global access is
//    lane-contiguous: t/out are dwordx3 at 12B stride (768B/instr, full lines),
//    weights are a coalesced float4 run over the L1-resident 4KB z-slice.
//    (Previous version had lanes at 48B stride -> ~3x TA/L1 request
//    amplification on every load and store.)
__global__ __launch_bounds__(256) void ecwl_kernel(
    const float* __restrict__ t,    // [P][B][C][3]
    const float* __restrict__ na,   // [B][Z]  (one-hot)
    const float* __restrict__ w,    // [Z][C][P]
    float* __restrict__ out)        // [B][C][3]
{
    const int lane = threadIdx.x & 63;
    const int b = (blockIdx.x << 2) + (threadIdx.x >> 6);
    if (b >= BNODES) return;

    // ---- one-hot index via wave ballot (coalesced 4B/lane read) ----
    const float nav = na[(size_t)b * ZDIM + lane];
    const unsigned long long m = __ballot(nav > 0.5f);
    const int idx = (m != 0ull) ? (__ffsll(m) - 1) : 0;   // clamp: never fault

    const float* __restrict__ wb = w + (size_t)idx * (CDIM * PDIM);  // 4KB slice, L1-hot
    const float* __restrict__ tb = t + (size_t)b * ROW;
    float* __restrict__ ob = out + (size_t)b * ROW;
    const size_t PS = (size_t)BNODES * ROW;   // p-stride in floats

    #pragma unroll
    for (int j = 0; j < 4; ++j) {
        const int c = (j << 6) | lane;        // contiguous across the wave

        // w[idx][c][0..3]: per-lane float4, stride-16B across lanes -> coalesced
        const float4 wv = *(const float4*)(wb + (c << 2));

        // t[p][b][c][0..2]: per-lane 12B, stride-12B across lanes -> contiguous 768B
        const f3 v0 = *(const f3*)(tb + 0 * PS + c * 3);
        const f3 v1 = *(const f3*)(tb + 1 * PS + c * 3);
        const f3 v2 = *(const f3*)(tb + 2 * PS + c * 3);
        const f3 v3 = *(const f3*)(tb + 3 * PS + c * 3);

        float ax = v0.x * wv.x, ay = v0.y * wv.x, az = v0.z * wv.x;
        ax = fmaf(v1.x, wv.y, ax); ay = fmaf(v1.y, wv.y, ay); az = fmaf(v1.z, wv.y, az);
        ax = fmaf(v2.x, wv.z, ax); ay = fmaf(v2.y, wv.z, ay); az = fmaf(v2.z, wv.z, az);
        ax = fmaf(v3.x, wv.w, ax); ay = fmaf(v3.y, wv.w, ay); az = fmaf(v3.z, wv.w, az);

        f3 o;
        o.x = ax * ALPHA; o.y = ay * ALPHA; o.z = az * ALPHA;
        *(f3*)(ob + c * 3) = o;               // contiguous 768B store per instr
    }
}

extern "C" void kernel_launch(void* const* d_in, const int* in_sizes, int n_in,
                              void* d_out, int out_size, void* d_ws, size_t ws_size,
                              hipStream_t stream) {
    const float* t  = (const float*)d_in[0];   // [P,B,C,3]
    const float* na = (const float*)d_in[1];   // [B,Z]
    const float* w  = (const float*)d_in[2];   // [Z,C,P]
    float* out = (float*)d_out;                // [B,C,3]

    // 4 waves per block, one wave per node: 50000 / 4 = 12500 blocks exactly
    dim3 grid((BNODES + 3) / 4);
    dim3 block(256);
    ecwl_kernel<<<grid, block, 0, stream>>>(t, na, w, out);
}